// Round 3
// baseline (186.985 us; speedup 1.0000x reference)
//
#include <hip/hip_runtime.h>
#include <hip/hip_bf16.h>
#include <math.h>

#define H 192
#define W 192
#define CIN 32
#define COUT 64
#define BATCH 16
#define HP 194                      // padded width (1 zero col each side)

// workspace: Wp[tap][co][ci] bf16 (36864 B) then accum f32 (4096 B)
#define WP_BYTES ((size_t)9 * COUT * CIN * 2)
#define ACC_OFF  WP_BYTES
#define ACC_BYTES ((size_t)BATCH * COUT * 4)

typedef __attribute__((ext_vector_type(8)))  short bf16x8;
typedef __attribute__((ext_vector_type(16))) float f32x16;

static __device__ __forceinline__ short f2bf(float f) {
  __hip_bfloat16 h = __float2bfloat16(f);
  return __builtin_bit_cast(short, h);
}

// LDS tile: [4 rows][194 wi][32 ci] bf16 = 49664 B, 16B granules g2 = ci>>3.
// XOR swizzle on byte addr (applied on BOTH write and read, bijective):
//   byte = r*12416 + wi*64 + g2*16;  byte ^= (wi&7)<<4;
// 8 consecutive-wi lanes -> 8 distinct 16B slots spanning 128 B = all 32 banks.
#define ROW_BYTES (HP * 64)
static __device__ __forceinline__ int lds_addr(int r, int wi, int g2) {
  int a = r * ROW_BYTES + wi * 64 + g2 * 16;
  return a ^ ((wi & 7) << 4);
}

// weight [ci][co][kh][kw] f32 -> Wp[tap][co][ci] bf16 (flipped kernel)
__global__ void pack_weights(const float* __restrict__ wsrc, short* __restrict__ wp) {
  const int idx = blockIdx.x * 256 + threadIdx.x;
  if (idx >= 9 * COUT * CIN) return;
  const int ci = idx & 31, co = (idx >> 5) & 63, tap = idx >> 11;
  const int a = tap / 3, d = tap % 3;
  wp[idx] = f2bf(wsrc[((ci * COUT + co) * 3 + (2 - a)) * 3 + (2 - d)]);
}

// Fused: stage 4 x-rows to LDS (bf16 channel-minor, swizzled, zero-padded),
// then implicit-GEMM conv + bias + maxpool2x2 + hardtanh + partial sum.
// grid (96 h-pairs, 16 b), 256 threads = 4 waves: wave&1 -> co half,
// wave>>1 -> w half; each wave: 3 w-tiles of 32 pixels x 2 conv rows x 32 co.
__global__ __launch_bounds__(256, 3)
void fused_conv(const float* __restrict__ x, const short* __restrict__ wp,
                const float* __restrict__ bias, float* __restrict__ accum) {
  __shared__ short lds[4 * HP * 32];          // 49664 B
  const int hp   = blockIdx.x;                // 0..95
  const int b    = blockIdx.y;                // 0..15
  const int tid  = threadIdx.x;
  const int wave = tid >> 6;
  const int l    = tid & 63;
  const int l31  = l & 31;
  const int lh   = l >> 5;                    // k-octet select
  const int co0  = (wave & 1) * 32;
  const int wh   = wave >> 1;
  const int h0   = hp * 2;

  // B fragments: 9 taps x 2 ci-halves; issued early, overlap with staging.
  bf16x8 bw[9][2];
  {
    const short* p = wp + (co0 + l31) * 32 + lh * 8;
    #pragma unroll
    for (int tap = 0; tap < 9; ++tap)
      #pragma unroll
      for (int hf = 0; hf < 2; ++hf)
        bw[tap][hf] = *(const bf16x8*)(p + tap * 2048 + hf * 16);
  }

  // ---- stage: wave `r` loads x row h0-1+r (all 32 ci, 192 w) -> LDS row r
  {
    const int r = wave;
    const int h = h0 - 1 + r;
    const bool hv = (unsigned)h < H;
    const int hc = hv ? h : 0;
    #pragma unroll
    for (int i = 0; i < 12; ++i) {
      const int g = i / 3;                    // ci octet 0..3
      const int w = (i % 3) * 64 + l;         // 0..191
      const float* src = x + (((size_t)(b * CIN + g * 8)) * H + hc) * W + w;
      bf16x8 o;
      #pragma unroll
      for (int j = 0; j < 8; ++j)
        o[j] = hv ? f2bf(src[(size_t)j * H * W]) : (short)0;
      *(bf16x8*)((char*)lds + lds_addr(r, 1 + w, g)) = o;
    }
  }
  // border columns wi=0 and wi=193 -> zero granules
  if (tid < 32) {
    const int r = tid >> 3, side = (tid >> 2) & 1, g2 = tid & 3;
    bf16x8 z = {0, 0, 0, 0, 0, 0, 0, 0};
    *(bf16x8*)((char*)lds + lds_addr(r, side ? (HP - 1) : 0, g2)) = z;
  }
  __syncthreads();

  const float bv = bias[co0 + l31];
  float sum = 0.f;

  for (int wt = 0; wt < 3; ++wt) {
    const int w0 = wh * 96 + wt * 32;
    f32x16 acc0, acc1;
    #pragma unroll
    for (int i = 0; i < 16; ++i) { acc0[i] = 0.f; acc1[i] = 0.f; }

    // LDS rows xr=0..3 feed conv rows h0 (acc0, a=xr) and h0+1 (acc1, a=xr-1)
    #pragma unroll
    for (int xr = 0; xr < 4; ++xr) {
      #pragma unroll
      for (int d = 0; d < 3; ++d) {
        const int wi = w0 + l31 + d;
        #pragma unroll
        for (int hf = 0; hf < 2; ++hf) {
          const bf16x8 af =
              *(const bf16x8*)((const char*)lds + lds_addr(xr, wi, 2 * hf + lh));
          if (xr < 3)
            acc0 = __builtin_amdgcn_mfma_f32_32x32x16_bf16(af, bw[xr * 3 + d][hf], acc0, 0, 0, 0);
          if (xr > 0)
            acc1 = __builtin_amdgcn_mfma_f32_32x32x16_bf16(af, bw[(xr - 1) * 3 + d][hf], acc1, 0, 0, 0);
        }
      }
    }

    // C row = (reg&3)+8*(reg>>2)+4*(l>>5): regs (2g,2g+1) are the w-pair,
    // acc0/acc1 the h-pair -> full 2x2 maxpool in-lane.
    #pragma unroll
    for (int g = 0; g < 8; ++g) {
      float m = fmaxf(fmaxf(acc0[2 * g], acc0[2 * g + 1]),
                      fmaxf(acc1[2 * g], acc1[2 * g + 1]));
      sum += fminf(fmaxf(m + bv, -1.f), 1.f);
    }
  }

  // lanes l and l^32 hold the same co, different pixels
  sum += __shfl_xor(sum, 32, 64);
  if (l < 32) atomicAdd(&accum[b * COUT + co0 + l31], sum);
}

__global__ void finish_kernel(const float* __restrict__ accum,
                              float* __restrict__ out, int n) {
  const int i = blockIdx.x * blockDim.x + threadIdx.x;
  if (i < n) out[i] = tanhf(accum[i] * (1.0f / (96.0f * 96.0f)));
}

extern "C" void kernel_launch(void* const* d_in, const int* in_sizes, int n_in,
                              void* d_out, int out_size, void* d_ws, size_t ws_size,
                              hipStream_t stream) {
  const float* x      = (const float*)d_in[0];
  const float* weight = (const float*)d_in[1];
  const float* bias   = (const float*)d_in[2];
  float* out = (float*)d_out;

  short* wp    = (short*)d_ws;
  float* accum = (float*)((char*)d_ws + ACC_OFF);

  hipMemsetAsync(accum, 0, ACC_BYTES, stream);
  pack_weights<<<dim3((9 * COUT * CIN + 255) / 256), 256, 0, stream>>>(weight, wp);
  fused_conv<<<dim3(96, BATCH), 256, 0, stream>>>(x, wp, bias, accum);
  finish_kernel<<<dim3((BATCH * COUT + 255) / 256), 256, 0, stream>>>(
      accum, out, BATCH * COUT);
}

// Round 4
// 163.954 us; speedup vs baseline: 1.1405x; 1.1405x over previous
//
#include <hip/hip_runtime.h>
#include <hip/hip_bf16.h>
#include <math.h>

#define H 192
#define W 192
#define CIN 32
#define COUT 64
#define BATCH 16
#define HP 194                      // padded row width (zero col each side)
#define NSLOT 6                     // LDS row ring
#define ROW_BYTES (HP * 64)         // one row-slot: 194 wi * 32 ci * 2B

#define WP_BYTES ((size_t)9 * COUT * CIN * 2)
#define ACC_OFF  WP_BYTES
#define ACC_BYTES ((size_t)BATCH * COUT * 4)

typedef __attribute__((ext_vector_type(8)))  short bf16x8;
typedef __attribute__((ext_vector_type(16))) float f32x16;

static __device__ __forceinline__ short f2bf(float f) {
  __hip_bfloat16 h = __float2bfloat16(f);
  return __builtin_bit_cast(short, h);
}

// LDS slot: [wi 0..193][ci-granule 0..3] bf16x8. XOR swizzle (both sides):
// byte = s*ROW_BYTES + wi*64 + g*16, byte ^= (wi&7)<<4 -> 8 consecutive-wi
// lanes hit 8 distinct 16B slots across all 32 banks (2-way alias = free).
static __device__ __forceinline__ int lds_addr(int s, int wi, int g) {
  int a = s * ROW_BYTES + wi * 64 + g * 16;
  return a ^ ((wi & 7) << 4);
}

// weight [ci][co][kh][kw] f32 -> Wp[tap][co][ci] bf16 (flipped kernel)
__global__ void pack_weights(const float* __restrict__ wsrc, short* __restrict__ wp) {
  const int idx = blockIdx.x * 256 + threadIdx.x;
  if (idx >= 9 * COUT * CIN) return;
  const int ci = idx & 31, co = (idx >> 5) & 63, tap = idx >> 11;
  const int a = tap / 3, d = tap % 3;
  wp[idx] = f2bf(wsrc[((ci * COUT + co) * 3 + (2 - a)) * 3 + (2 - d)]);
}

// Fused conv-transpose + bias + maxpool2x2 + hardtanh + partial sum.
// grid (32 h-groups, 16 b), 256 threads = 4 waves. Each block: 6 conv rows
// (3 h-pairs), rolling 6-slot LDS ring of x-rows (bf16, channel-minor,
// swizzled). Per h-pair iteration (T14 async-split):
//   [issue next 2 x-rows -> regs] [MFMA compute] [bar] [cvt+ds_write] [bar]
__global__ __launch_bounds__(256, 2)
void fused_conv(const float* __restrict__ x, const short* __restrict__ wp,
                const float* __restrict__ bias, float* __restrict__ accum) {
  __shared__ short lds[NSLOT * HP * 32];      // 74496 B -> 2 blocks/CU
  const int hg    = blockIdx.x;               // 0..31
  const int b     = blockIdx.y;               // 0..15
  const int tid   = threadIdx.x;
  const int wave  = tid >> 6;
  const int l     = tid & 63;
  const int l31   = l & 31;
  const int lh    = l >> 5;                   // k-octet select
  const int co0   = (wave & 1) * 32;          // compute mapping
  const int wh    = wave >> 1;
  const int hbase = hg * 6;

  // B fragments: 9 taps x 2 ci-halves (36 VGPRs), loaded once.
  bf16x8 bw[9][2];
  {
    const short* p = wp + (co0 + l31) * 32 + lh * 8;
    #pragma unroll
    for (int tap = 0; tap < 9; ++tap)
      #pragma unroll
      for (int hf = 0; hf < 2; ++hf)
        bw[tap][hf] = *(const bf16x8*)(p + tap * 2048 + hf * 16);
  }

  // zero border columns (wi=0, wi=193) once for all 6 slots
  if (tid < 48) {
    const int s = tid >> 3, side = (tid >> 2) & 1, g = tid & 3;
    bf16x8 z = {0, 0, 0, 0, 0, 0, 0, 0};
    *(bf16x8*)((char*)lds + lds_addr(s, side ? (HP - 1) : 0, g)) = z;
  }

  // prologue: wave r stages local x-row (r-1) -> slot (r+5)%6
  {
    const int lr = wave - 1;
    const int s  = (wave + 5) % 6;
    const int hx = hbase + lr;
    const bool hv = (unsigned)hx < H;
    const int hc = hv ? hx : 0;
    #pragma unroll
    for (int i = 0; i < 12; ++i) {
      const int g = i / 3;                    // ci octet
      const int w = (i % 3) * 64 + l;
      const float* src = x + (((size_t)(b * CIN + g * 8)) * H + hc) * W + w;
      bf16x8 o;
      #pragma unroll
      for (int j = 0; j < 8; ++j)
        o[j] = hv ? f2bf(src[(size_t)j * (H * W)]) : (short)0;
      *(bf16x8*)((char*)lds + lds_addr(s, 1 + w, g)) = o;
    }
  }
  __syncthreads();

  const float bv = bias[co0 + l31];
  float sum = 0.f;

  // staging role (independent of compute mapping): 2 waves per row
  const int rw  = wave >> 1;                  // which of the 2 new rows
  const int sub = wave & 1;                   // ci-octet half

  #pragma unroll
  for (int t = 0; t < 3; ++t) {
    // ---- T14 phase A: issue global loads for x-rows 2t+3, 2t+4 -> regs
    float st[6][8];
    const int lr = 2 * t + 3 + rw;
    const int hx = hbase + lr;
    const bool hv = hx < H;
    const int hc = hv ? hx : 0;
    if (t < 2) {
      #pragma unroll
      for (int g2 = 0; g2 < 2; ++g2)
        #pragma unroll
        for (int w3 = 0; w3 < 3; ++w3) {
          const int g = sub * 2 + g2;
          const int w = w3 * 64 + l;
          const float* src = x + (((size_t)(b * CIN + g * 8)) * H + hc) * W + w;
          #pragma unroll
          for (int j = 0; j < 8; ++j)
            st[g2 * 3 + w3][j] = src[(size_t)j * (H * W)];
        }
    }

    // ---- phase B: compute h-pair t (conv rows hbase+2t, +1)
    __builtin_amdgcn_s_setprio(1);
    #pragma unroll
    for (int wt = 0; wt < 3; ++wt) {
      const int w0 = wh * 96 + wt * 32;
      f32x16 acc0, acc1;
      #pragma unroll
      for (int i = 0; i < 16; ++i) { acc0[i] = 0.f; acc1[i] = 0.f; }

      #pragma unroll
      for (int xr = 0; xr < 4; ++xr) {
        const int s = (2 * t + 5 + xr) % 6;   // unroll-constant slot
        #pragma unroll
        for (int d = 0; d < 3; ++d) {
          const int wi = w0 + l31 + d;
          #pragma unroll
          for (int hf = 0; hf < 2; ++hf) {
            const bf16x8 af =
                *(const bf16x8*)((const char*)lds + lds_addr(s, wi, 2 * hf + lh));
            if (xr < 3)
              acc0 = __builtin_amdgcn_mfma_f32_32x32x16_bf16(af, bw[xr * 3 + d][hf], acc0, 0, 0, 0);
            if (xr > 0)
              acc1 = __builtin_amdgcn_mfma_f32_32x32x16_bf16(af, bw[(xr - 1) * 3 + d][hf], acc1, 0, 0, 0);
          }
        }
      }

      // C row = (reg&3)+8*(reg>>2)+4*lh: regs (2g,2g+1) = w-pair,
      // acc0/acc1 = h-pair -> full 2x2 maxpool in-lane.
      #pragma unroll
      for (int g = 0; g < 8; ++g) {
        float m = fmaxf(fmaxf(acc0[2 * g], acc0[2 * g + 1]),
                        fmaxf(acc1[2 * g], acc1[2 * g + 1]));
        sum += fminf(fmaxf(m + bv, -1.f), 1.f);
      }
    }
    __builtin_amdgcn_s_setprio(0);

    // ---- phase C: land staged rows into ring slots (disjoint from read set)
    if (t < 2) {
      __syncthreads();                         // also drains vmcnt for st[]
      #pragma unroll
      for (int g2 = 0; g2 < 2; ++g2)
        #pragma unroll
        for (int w3 = 0; w3 < 3; ++w3) {
          bf16x8 o;
          #pragma unroll
          for (int j = 0; j < 8; ++j)
            o[j] = hv ? f2bf(st[g2 * 3 + w3][j]) : (short)0;
          const int s = (2 * t + 3 + rw) % 6;
          *(bf16x8*)((char*)lds + lds_addr(s, 1 + w3 * 64 + l, sub * 2 + g2)) = o;
        }
      __syncthreads();
    }
  }

  // lanes l and l^32 hold the same co, different pixels
  sum += __shfl_xor(sum, 32, 64);
  if (l < 32) atomicAdd(&accum[b * COUT + co0 + l31], sum);
}

__global__ void finish_kernel(const float* __restrict__ accum,
                              float* __restrict__ out, int n) {
  const int i = blockIdx.x * blockDim.x + threadIdx.x;
  if (i < n) out[i] = tanhf(accum[i] * (1.0f / (96.0f * 96.0f)));
}

extern "C" void kernel_launch(void* const* d_in, const int* in_sizes, int n_in,
                              void* d_out, int out_size, void* d_ws, size_t ws_size,
                              hipStream_t stream) {
  const float* x      = (const float*)d_in[0];
  const float* weight = (const float*)d_in[1];
  const float* bias   = (const float*)d_in[2];
  float* out = (float*)d_out;

  short* wp    = (short*)d_ws;
  float* accum = (float*)((char*)d_ws + ACC_OFF);

  hipMemsetAsync(accum, 0, ACC_BYTES, stream);
  pack_weights<<<dim3((9 * COUT * CIN + 255) / 256), 256, 0, stream>>>(weight, wp);
  fused_conv<<<dim3(32, BATCH), 256, 0, stream>>>(x, wp, bias, accum);
  finish_kernel<<<dim3((BATCH * COUT + 255) / 256), 256, 0, stream>>>(
      accum, out, BATCH * COUT);
}